// Round 14
// baseline (184.985 us; speedup 1.0000x reference)
//
#include <hip/hip_runtime.h>
#include <math.h>

// Problem constants: x [4, 256, 64, 64] fp32
#define BB   4
#define CC   256
#define NN   4096      // 64*64 spatial
#define GG   8
#define CPG  32        // channels per group
#define EPSV 1e-5f
#define SCALE 0.0625f  // 1/sqrt(256)
#define LOG2E 1.44269504089f
#define NSPLIT 4

typedef __attribute__((ext_vector_type(8))) short bf16x8;  // 8 bf16 = 4 VGPRs
typedef __attribute__((ext_vector_type(4))) float f32x4;

struct alignas(8) us4 { unsigned short x, y, z, w; };

static __device__ __forceinline__ unsigned short f2bf(float f) {
    union { float f; unsigned int u; } a; a.f = f;
    unsigned int r = a.u + 0x7fffu + ((a.u >> 16) & 1u);   // RNE
    return (unsigned short)(r >> 16);
}
// native exp2 (v_exp_f32). NOTE: __exp2f collides with glibc math.h macros
// on this toolchain (R13 compile failure) — use the amdgcn builtin directly.
static __device__ __forceinline__ float ex2(float f) {
    return __builtin_amdgcn_exp2f(f);
}
// async global->LDS, 16B/lane: per-lane gptr, wave-uniform LDS base (+lane*16 by HW)
static __device__ __forceinline__ void async16(const unsigned short* g, unsigned short* l) {
    __builtin_amdgcn_global_load_lds(
        (const __attribute__((address_space(1))) unsigned int*)g,
        (__attribute__((address_space(3))) unsigned int*)l,
        16, 0, 0);
}

// Chunked fragment layout for an R x 256 bf16 matrix:
//   chunk id = (r>>4)*8 + (c>>5); 512 us per chunk;
//   interior  = (((c&31)>>3)*16 + (r&15))*8 + (c&7)   == lane*8 + j for the
//   MFMA fragment. Every fragment is 64 lanes x 16 B contiguous.
//
// K-tile key permutation (R12): within each 32-key attn tile, ksw stores
// sub-tile jg row j' = ORIGINAL key 8*(j'>>2) + 4*jg + (j'&3). Then the
// S^T MFMA output at lane (lrow,quad), slots [jg=0 r0..r3, jg=1 r0..r3]
// is keys [8q..8q+7] -> exactly the PV A-fragment, in order, in-lane.
// V and Q stay in original order (contraction index carries key identity).
//
// R13: Q is scaled by SCALE*log2(e) in qkv, so attn computes p = exp2(s)
// with the native v_exp_f32 (no per-element pre-multiply).

// ---------------------------------------------------------------------------
// K0: merged prep: blocks 0..255 = GroupNorm partial stats; 256..511 = weight
// fp32->bf16 conversion into CHUNKED layout.
// ---------------------------------------------------------------------------
__global__ __launch_bounds__(256) void prep_kernel(
    const float* __restrict__ x, const float* __restrict__ w_qkv,
    const float* __restrict__ w_proj, float* __restrict__ partials,
    unsigned short* __restrict__ wbf)
{
    const int tid = threadIdx.x;
    if (blockIdx.x >= 256) {
        int idx = ((blockIdx.x - 256)*256 + tid) * 4;     // 0..262140
        float4 v;
        if (idx < 196608) v = *(const float4*)(w_qkv + idx);
        else              v = *(const float4*)(w_proj + (idx - 196608));
        us4 h = { f2bf(v.x), f2bf(v.y), f2bf(v.z), f2bf(v.w) };
        int o = idx >> 8, c = idx & 255;
        size_t dst = ((size_t)((o >> 4)*8 + (c >> 5)))*512
                   + ((((c & 31) >> 3))*16 + (o & 15))*8 + (c & 7);
        *(us4*)(wbf + dst) = h;
        return;
    }
    const int bg = blockIdx.x >> 3, slice = blockIdx.x & 7;
    const float4* base = (const float4*)(x + (size_t)bg*CPG*NN + slice*16384);
    float s = 0.f, sq = 0.f;
    for (int i = tid; i < 4096; i += 256) {
        float4 v = base[i];
        s  += v.x + v.y + v.z + v.w;
        sq += v.x*v.x + v.y*v.y + v.z*v.z + v.w*v.w;
    }
    __shared__ float ls[256], lq[256];
    ls[tid] = s; lq[tid] = sq;
    __syncthreads();
    for (int off = 128; off > 0; off >>= 1) {
        if (tid < off) { ls[tid] += ls[tid+off]; lq[tid] += lq[tid+off]; }
        __syncthreads();
    }
    if (tid == 0) { partials[blockIdx.x*2] = ls[0]; partials[blockIdx.x*2+1] = lq[0]; }
}

// ---------------------------------------------------------------------------
// K2: normalize + transpose: x [b][c][n] fp32 -> xnT CHUNKED bf16.
// ---------------------------------------------------------------------------
__global__ __launch_bounds__(256) void norm_t_kernel(
    const float* __restrict__ x, const float* __restrict__ gamma,
    const float* __restrict__ beta, const float* __restrict__ partials,
    unsigned short* __restrict__ xnT)
{
    const int n0 = blockIdx.x * 64;
    const int c0 = blockIdx.y * 64;
    const int b  = blockIdx.z;
    const int tid = threadIdx.x;
    __shared__ unsigned short T[64*68];
    __shared__ float ssc[64], ssh[64];
    if (tid < 64) {
        int c = c0 + tid;
        int bg = b*GG + (c >> 5);
        float s = 0.f, sq = 0.f;
        for (int i = 0; i < 8; i++) {
            s  += partials[(bg*8 + i)*2];
            sq += partials[(bg*8 + i)*2 + 1];
        }
        const float cnt = (float)(CPG*NN);
        float mean = s / cnt;
        float var  = sq / cnt - mean*mean;
        float rstd = rsqrtf(var + EPSV);
        float g = gamma[c], be = beta[c];
        ssc[tid] = rstd*g;
        ssh[tid] = be - mean*rstd*g;
    }
    __syncthreads();
    {
        int cl = tid >> 4, n4 = tid & 15;
        for (int i = 0; i < 4; i++) {
            int c = cl + i*16;
            float4 v = *(const float4*)(x + ((size_t)(b*CC + c0 + c))*NN + n0 + n4*4);
            float sc = ssc[c], sh = ssh[c];
            T[(n4*4+0)*68 + c] = f2bf(v.x*sc + sh);
            T[(n4*4+1)*68 + c] = f2bf(v.y*sc + sh);
            T[(n4*4+2)*68 + c] = f2bf(v.z*sc + sh);
            T[(n4*4+3)*68 + c] = f2bf(v.w*sc + sh);
        }
    }
    __syncthreads();
    {
        int nl = tid >> 3, cs = tid & 7;
        for (int i = 0; i < 2; i++) {
            int n = nl + i*32;                       // block-local row
            int gg = (b*NN + n0 + n) >> 4;           // global 16-row group
            int kk = (c0 >> 5) + (cs >> 2);          // 32-col group
            size_t dst = ((size_t)(gg*8 + kk))*512 + ((cs & 3)*16 + (n & 15))*8;
            *(bf16x8*)(xnT + dst) = *(const bf16x8*)&T[n*68 + cs*8];
        }
    }
}

// ---------------------------------------------------------------------------
// K3: QKV MFMA GEMM, R9 staging + R12 K-permutation + R13 sync slimming:
// for Q/K blocks (which 0,1) the lx dbuf is wave-private (each wave DMAs
// exactly the 2 chunks it reads) and lw is read-only after the prologue ->
// per-kk barrier dropped; per-wave vmcnt(0) suffices. isV keeps the barrier
// (af reads cross-wave lx chunks). One barrier added before epilogue lw reuse.
// ---------------------------------------------------------------------------
__global__ __launch_bounds__(256, 3) void qkv_mfma_kernel(
    const unsigned short* __restrict__ xnT, const unsigned short* __restrict__ wbf,
    const float* __restrict__ b_qkv,
    unsigned short* __restrict__ qsw, unsigned short* __restrict__ ksw,
    unsigned short* __restrict__ vsw)
{
    const int tid  = threadIdx.x;
    const int wave = tid >> 6, lane = tid & 63;
    const int lrow = lane & 15, quad = lane >> 4;
    const int R0   = blockIdx.x * 128;
    const int b    = blockIdx.x >> 5;
    const int nb0  = (blockIdx.x & 31) * 128;
    const int oBase = blockIdx.y * 64;
    const int which = oBase >> 8;
    const int o0l   = oBase & 255;
    const bool isV  = (which == 2);
    const bool isK  = (which == 1);
    const int wn = wave >> 1, wo = wave & 1;
    const int wg0 = oBase >> 4;                    // weight 16-row group base

    __shared__ unsigned short lw[16384];           // 32 KB: weights (4g x 8kk)
    __shared__ unsigned short lx[2][4096];         // 16 KB: xnT kk-tile dbuf

    // prologue: stage weights (8 chunks/wave) + xnT kk=0 tile (2 chunks/wave)
    const unsigned short* wsrc = wbf + ((size_t)(wg0 + wave))*8*512 + lane*8;
    for (int kk = 0; kk < 8; kk++)
        async16(wsrc + kk*512, lw + (wave*8 + kk)*512);
    const unsigned short* xsrc = xnT + (size_t)R0*CC + lane*8;   // == (R0>>4)*8*512
    for (int i = 0; i < 2; i++) {
        int g = wave*2 + i;
        async16(xsrc + (size_t)g*4096, lx[0] + g*512);
    }
    asm volatile("s_waitcnt vmcnt(0)" ::: "memory");
    __builtin_amdgcn_s_barrier();

    f32x4 acc[4][2];
    for (int s = 0; s < 4; s++) for (int t = 0; t < 2; t++)
        acc[s][t] = (f32x4){0.f, 0.f, 0.f, 0.f};

    for (int kk = 0; kk < 8; kk++) {
        const int cur = kk & 1, nxt = cur ^ 1;
        if (kk + 1 < 8) {
            for (int i = 0; i < 2; i++) {
                int g = wave*2 + i;
                async16(xsrc + (size_t)g*4096 + (kk+1)*512, lx[nxt] + g*512);
            }
        }
        bf16x8 af[4], bfr[2];
        if (!isV) {
            for (int s = 0; s < 4; s++)
                af[s]  = *(const bf16x8*)(lw + (s*8 + kk)*512 + lane*8);
            for (int t = 0; t < 2; t++)
                bfr[t] = *(const bf16x8*)(lx[cur] + (wave*2 + t)*512 + lane*8);
        } else {
            for (int s = 0; s < 4; s++)
                af[s]  = *(const bf16x8*)(lx[cur] + (wn*4 + s)*512 + lane*8);
            for (int t = 0; t < 2; t++)
                bfr[t] = *(const bf16x8*)(lw + ((wo*2 + t)*8 + kk)*512 + lane*8);
        }
        __builtin_amdgcn_s_setprio(1);
        for (int s = 0; s < 4; s++)
            for (int t = 0; t < 2; t++)
                acc[s][t] = __builtin_amdgcn_mfma_f32_16x16x32_bf16(af[s], bfr[t], acc[s][t], 0, 0, 0);
        __builtin_amdgcn_s_setprio(0);
        if (isV) {
            // cross-wave lx reads: full drain + barrier per kk (as before)
            asm volatile("s_waitcnt vmcnt(0) lgkmcnt(0)" ::: "memory");
            __builtin_amdgcn_s_barrier();
        } else {
            // wave-private dbuf: only this wave's DMAs must land before the
            // next iteration reads lx[nxt]. No barrier needed.
            asm volatile("s_waitcnt vmcnt(0)" ::: "memory");
        }
    }

    // epilogue: reuse lw as 8192-us scratch.
    // !isV path dropped per-kk barriers -> resync before overwriting lw
    // (other waves may still be reading lw in their last iteration).
    if (!isV) __syncthreads();
    unsigned short* lds = lw;

    if (!isV) {
        // Q gets SCALE*log2(e) so attention can use native exp2.
        const float sc = (which == 0) ? (SCALE * LOG2E) : 1.0f;
        for (int s = 0; s < 4; s++) {
            float bias[4];
            for (int r = 0; r < 4; r++) bias[r] = b_qkv[oBase + s*16 + quad*4 + r];
            for (int t = 0; t < 2; t++) {
                us4 h;
                h.x = f2bf((acc[s][t][0] + bias[0]) * sc);
                h.y = f2bf((acc[s][t][1] + bias[1]) * sc);
                h.z = f2bf((acc[s][t][2] + bias[2]) * sc);
                h.w = f2bf((acc[s][t][3] + bias[3]) * sc);
                int chunk, pos;
                if (!isK) {
                    // Q: original layout (key = t*16 + lrow in order)
                    chunk = (wave*2 + t)*2 + (s>>1);
                    pos = (((s*2 + (quad>>1)) & 3)*16 + lrow)*8 + (quad&1)*4;
                } else {
                    // K: permuted key order (R12) -> S^T output slots become
                    // the PV A-fragment in-lane.
                    int gp = (lrow >> 2) & 1;
                    int jp = t*8 + ((lrow >> 3) << 2) + (lrow & 3);
                    chunk = (wave*2 + gp)*2 + (s>>1);
                    pos = (((s*2 + (quad>>1)) & 3)*16 + jp)*8 + (quad&1)*4;
                }
                *(us4*)&lds[chunk*512 + pos] = h;
            }
        }
    } else {
        for (int s = 0; s < 4; s++)
            for (int t = 0; t < 2; t++) {
                int oc = o0l + wo*32 + t*16 + lrow;
                float bias = b_qkv[512 + oc];
                us4 h;
                h.x = f2bf(acc[s][t][0] + bias);
                h.y = f2bf(acc[s][t][1] + bias);
                h.z = f2bf(acc[s][t][2] + bias);
                h.w = f2bf(acc[s][t][3] + bias);
                int chunk = (wn*2 + (s>>1))*4 + wo*2 + t;
                int pos = (((s&1)*2 + (quad>>1))*16 + lrow)*8 + (quad&1)*4;
                *(us4*)&lds[chunk*512 + pos] = h;
            }
    }
    __syncthreads();

    if (!isV) {
        unsigned short* dst = (which == 0) ? qsw : ksw;
        for (int it = 0; it < 4; it++) {
            int f = it*4 + (tid>>6);
            int ng_l = f >> 1, kk_l = f & 1;
            size_t off = ((size_t)(b*256 + (nb0>>4) + ng_l)*8 + (o0l>>5) + kk_l)*512 + lane*8;
            *(bf16x8*)(dst + off) = *(const bf16x8*)&lds[f*512 + lane*8];
        }
    } else {
        for (int it = 0; it < 4; it++) {
            int f = it*4 + (tid>>6);
            int jg_l = f >> 2, ns_l = f & 3;
            size_t off = ((size_t)(b*128 + (nb0>>5) + jg_l)*16 + (o0l>>4) + ns_l)*512 + lane*8;
            *(bf16x8*)(vsw + off) = *(const bf16x8*)&lds[f*512 + lane*8];
        }
    }
}

// ---------------------------------------------------------------------------
// K4: MFMA flash attention — R11 XCD swizzle + R12 in-register P + R13 exp2.
// Q pre-scaled by SCALE*log2e -> p = exp2(s) via native v_exp_f32 (no muls).
// ---------------------------------------------------------------------------
__global__ __launch_bounds__(256, 2) void attn_mfma_kernel(
    const unsigned short* __restrict__ qsw, const unsigned short* __restrict__ ksw,
    const unsigned short* __restrict__ vsw,
    unsigned short* __restrict__ opart, float* __restrict__ lpart)
{
    const int tid  = threadIdx.x;
    const int wave = tid >> 6, lane = tid & 63;
    const int lrow = lane & 15, quad = lane >> 4;
    const int bx    = blockIdx.x;
    const int sl    = bx & 15;                 // slice id (b*4 + split)
    const int ig    = bx >> 4;                 // 0..31
    const int split = sl & 3;
    const int b     = sl >> 2;
    const int i0w   = ig*128 + wave*32;
    const int koff  = split * (NN / NSPLIT);   // 0,1024,2048,3072
    const int NT    = (NN / NSPLIT) / 32;      // 32 tiles

    __shared__ unsigned short ldsK[2][8192];       // 32 KB: K double buf
    __shared__ unsigned short ldsV[2][8192];       // 32 KB: V double buf

    bf16x8 qf[2][8];
    {
        const unsigned short* qb = qsw + ((size_t)b << 20) + (size_t)i0w*256 + lane*8;
        for (int g = 0; g < 2; g++)
            for (int kk = 0; kk < 8; kk++)
                qf[g][kk] = *(const bf16x8*)(qb + g*4096 + kk*512);
    }

    f32x4 o_acc[2][16];
    for (int g = 0; g < 2; g++)
        for (int ns = 0; ns < 16; ns++)
            o_acc[g][ns] = (f32x4){0.f, 0.f, 0.f, 0.f};
    float lsum[2] = {0.f, 0.f};

    const unsigned short* kp = ksw + ((size_t)b << 20) + (size_t)koff*256 + wave*2048 + lane*8;
    const unsigned short* vp = vsw + ((size_t)b << 20) + (size_t)koff*256 + wave*2048 + lane*8;

    // prologue: stage tile 0 into buffer 0
    for (int t = 0; t < 4; t++) {
        async16(kp + t*512, ldsK[0] + wave*2048 + t*512);
        async16(vp + t*512, ldsV[0] + wave*2048 + t*512);
    }
    asm volatile("s_waitcnt vmcnt(0)" ::: "memory");
    __builtin_amdgcn_s_barrier();

    for (int jt = 0; jt < NT; jt++) {
        const int cur = jt & 1, nxt = cur ^ 1;

        if (jt + 1 < NT) {
            for (int t = 0; t < 4; t++) {
                async16(kp + (size_t)(jt+1)*8192 + t*512, ldsK[nxt] + wave*2048 + t*512);
                async16(vp + (size_t)(jt+1)*8192 + t*512, ldsV[nxt] + wave*2048 + t*512);
            }
        }

        // ---- S^T = K Q^T (keys arrive permuted: slot (jg,quad,r) = key
        // 8*quad + 4*jg + r)
        f32x4 s[2][2];   // [jg key-subtile][g query-group]
        for (int jg = 0; jg < 2; jg++)
            for (int g = 0; g < 2; g++)
                s[jg][g] = (f32x4){0.f, 0.f, 0.f, 0.f};
        const unsigned short* lk = ldsK[cur];
        __builtin_amdgcn_s_setprio(1);
        for (int jg = 0; jg < 2; jg++)
            for (int kk = 0; kk < 8; kk++) {
                bf16x8 kf = *(const bf16x8*)(lk + (jg*8 + kk)*512 + lane*8);
                s[jg][0] = __builtin_amdgcn_mfma_f32_16x16x32_bf16(kf, qf[0][kk], s[jg][0], 0, 0, 0);
                s[jg][1] = __builtin_amdgcn_mfma_f32_16x16x32_bf16(kf, qf[1][kk], s[jg][1], 0, 0, 0);
            }
        __builtin_amdgcn_s_setprio(0);

        // ---- p = exp2(s) (Q pre-scaled by log2e) -> PV A-frags in-register.
        bf16x8 pa[2];
        for (int g = 0; g < 2; g++) {
            float p0 = ex2(s[0][g][0]);
            float p1 = ex2(s[0][g][1]);
            float p2 = ex2(s[0][g][2]);
            float p3 = ex2(s[0][g][3]);
            float p4 = ex2(s[1][g][0]);
            float p5 = ex2(s[1][g][1]);
            float p6 = ex2(s[1][g][2]);
            float p7 = ex2(s[1][g][3]);
            lsum[g] += p0 + p1 + p2 + p3 + p4 + p5 + p6 + p7;
            union { bf16x8 v; unsigned int w[4]; } u;
            u.w[0] = (unsigned int)f2bf(p0) | ((unsigned int)f2bf(p1) << 16);
            u.w[1] = (unsigned int)f2bf(p2) | ((unsigned int)f2bf(p3) << 16);
            u.w[2] = (unsigned int)f2bf(p4) | ((unsigned int)f2bf(p5) << 16);
            u.w[3] = (unsigned int)f2bf(p6) | ((unsigned int)f2bf(p7) << 16);
            pa[g] = u.v;
        }

        const unsigned short* lv = ldsV[cur];
        __builtin_amdgcn_s_setprio(1);
        for (int ns = 0; ns < 16; ns++) {
            bf16x8 vf = *(const bf16x8*)(lv + ns*512 + lane*8);
            o_acc[0][ns] = __builtin_amdgcn_mfma_f32_16x16x32_bf16(pa[0], vf, o_acc[0][ns], 0, 0, 0);
            o_acc[1][ns] = __builtin_amdgcn_mfma_f32_16x16x32_bf16(pa[1], vf, o_acc[1][ns], 0, 0, 0);
        }
        __builtin_amdgcn_s_setprio(0);

        asm volatile("s_waitcnt vmcnt(0) lgkmcnt(0)" ::: "memory");
        __builtin_amdgcn_s_barrier();
    }

    for (int g = 0; g < 2; g++) {
        float v = lsum[g];
        v += __shfl_xor(v, 16);
        v += __shfl_xor(v, 32);
        lsum[g] = v;
    }

    // epilogue: bounce O through LDS into frag-chunk layout, store b128.
    unsigned short* reg = &ldsV[0][0] + wave*4096;
    const size_t planeb = ((size_t)(split*BB + b)) << 20;
    for (int g = 0; g < 2; g++) {
        for (int ns = 0; ns < 16; ns++) {
            int kk = ns >> 1;
            int posbase = ((ns & 1)*2 + (lrow >> 3))*128 + (lrow & 7) + quad*32;
            for (int r = 0; r < 4; r++)
                reg[kk*512 + posbase + r*8] = f2bf(o_acc[g][ns][r]);
        }
        unsigned short* dst = opart + planeb + ((size_t)((i0w >> 4) + g))*4096;
        for (int kk = 0; kk < 8; kk++)
            *(bf16x8*)(dst + kk*512 + lane*8) = *(const bf16x8*)(reg + kk*512 + lane*8);
    }
    if (quad == 0)
        for (int g = 0; g < 2; g++)
            lpart[(size_t)(split*BB + b)*NN + i0w + g*16 + lrow] = lsum[g];
}

// ---------------------------------------------------------------------------
// K5: proj MFMA, R9 structure: async16 staging of opart (wave-private,
// no barriers). Block = 64 n x 64 o, grid 1024, 4 blocks/CU.
// ---------------------------------------------------------------------------
__global__ __launch_bounds__(256, 4) void proj_mfma_kernel(
    const unsigned short* __restrict__ opart, const float* __restrict__ lpart,
    const unsigned short* __restrict__ w2bf, const float* __restrict__ b_proj,
    const float* __restrict__ x, float* __restrict__ out)
{
    const int tid  = threadIdx.x;
    const int wave = tid >> 6, lane = tid & 63;
    const int lrow = lane & 15, quad = lane >> 4;
    const int rt = blockIdx.x & 255;           // row-tile (64 rows)
    const int oq = blockIdx.x >> 8;            // o-quarter (64 outs)
    const int b  = rt >> 6;
    const int n0 = (rt & 63) * 64;

    const int rg = (n0 >> 4) + wave;           // 16-row group within batch
    const unsigned short* Ab = opart + ((size_t)b << 20) + (size_t)rg*4096 + lane*8;
    const size_t pstride = (size_t)BB << 20;   // split-plane stride (us)

    __shared__ unsigned short la[2][8192];     // 32 KB dbuf: 16 chunks (w*4+sp)

    // prologue: stage kk=0 (wave-private: own rg, 4 split planes)
    for (int sp = 0; sp < NSPLIT; sp++)
        async16(Ab + (size_t)sp*pstride, la[0] + (wave*4 + sp)*512);
    asm volatile("s_waitcnt vmcnt(0)" ::: "memory");

    f32x4 acc[4];
    for (int t = 0; t < 4; t++) acc[t] = (f32x4){0.f, 0.f, 0.f, 0.f};

    for (int kk = 0; kk < 8; kk++) {
        const int cur = kk & 1, nxt = cur ^ 1;
        if (kk + 1 < 8)
            for (int sp = 0; sp < NSPLIT; sp++)
                async16(Ab + (size_t)sp*pstride + (kk+1)*512, la[nxt] + (wave*4 + sp)*512);

        bf16x8 bfr[4];
        for (int t = 0; t < 4; t++)
            bfr[t] = *(const bf16x8*)(w2bf + ((size_t)((oq*4 + t)*8 + kk))*512 + lane*8);

        __builtin_amdgcn_s_setprio(1);
        for (int sp = 0; sp < NSPLIT; sp++) {
            bf16x8 af = *(const bf16x8*)(la[cur] + (wave*4 + sp)*512 + lane*8);
            for (int t = 0; t < 4; t++)
                acc[t] = __builtin_amdgcn_mfma_f32_16x16x32_bf16(af, bfr[t], acc[t], 0, 0, 0);
        }
        __builtin_amdgcn_s_setprio(0);

        // per-wave drain: wave-private LDS regions -> no barrier anywhere.
        asm volatile("s_waitcnt vmcnt(0)" ::: "memory");
    }

    float sinv[4];
    for (int r = 0; r < 4; r++) {
        int n = n0 + wave*16 + quad*4 + r;
        float l = 0.f;
        for (int sp = 0; sp < NSPLIT; sp++)
            l += lpart[(size_t)(sp*BB + b)*NN + n];
        sinv[r] = 1.0f / l;
    }

    for (int t = 0; t < 4; t++) {
        int o = oq*64 + t*16 + lrow;
        int n = n0 + wave*16 + quad*4;
        size_t idx = ((size_t)(b*CC + o))*NN + n;
        float bias = b_proj[o];
        float4 xv = *(const float4*)(x + idx);
        float4 ov;
        ov.x = acc[t][0]*sinv[0] + bias + xv.x;
        ov.y = acc[t][1]*sinv[1] + bias + xv.y;
        ov.z = acc[t][2]*sinv[2] + bias + xv.z;
        ov.w = acc[t][3]*sinv[3] + bias + xv.w;
        *(float4*)(out + idx) = ov;
    }
}

// ---------------------------------------------------------------------------
extern "C" void kernel_launch(void* const* d_in, const int* in_sizes, int n_in,
                              void* d_out, int out_size, void* d_ws, size_t ws_size,
                              hipStream_t stream) {
    const float* x      = (const float*)d_in[0];
    const float* gamma  = (const float*)d_in[1];
    const float* beta   = (const float*)d_in[2];
    const float* w_qkv  = (const float*)d_in[3];
    const float* b_qkv  = (const float*)d_in[4];
    const float* w_proj = (const float*)d_in[5];
    const float* b_proj = (const float*)d_in[6];
    float* out = (float*)d_out;

    const size_t plane = (size_t)BB * NN * CC;     // 4,194,304 elems
    unsigned short* xnT = (unsigned short*)d_ws;
    unsigned short* qsw = xnT + plane;
    unsigned short* ksw = qsw + plane;
    unsigned short* vsw = ksw + plane;
    unsigned short* wbf = vsw + plane;             // 262144 us (chunked)
    unsigned short* opart = wbf + 262144;          // NSPLIT*plane us (bf16)
    float* lpart    = (float*)(opart + (size_t)NSPLIT*plane);  // NSPLIT*BB*NN
    float* partials = lpart + (size_t)NSPLIT*BB*NN;            // 512

    prep_kernel<<<512, 256, 0, stream>>>(x, w_qkv, w_proj, partials, wbf);

    dim3 gnt(64, 4, BB);
    norm_t_kernel<<<gnt, 256, 0, stream>>>(x, gamma, beta, partials, xnT);

    dim3 gq(128, 12);
    qkv_mfma_kernel<<<gq, 256, 0, stream>>>(xnT, wbf, b_qkv, qsw, ksw, vsw);

    attn_mfma_kernel<<<BB*32*NSPLIT, 256, 0, stream>>>(qsw, ksw, vsw, opart, lpart);

    proj_mfma_kernel<<<1024, 256, 0, stream>>>(opart, lpart, wbf + 196608, b_proj, x, out);
}